// Round 1
// baseline (1515.542 us; speedup 1.0000x reference)
//
#include <hip/hip_runtime.h>
#include <hip/hip_bf16.h>

#define BN_EPS 1e-3f

// ---------------------------------------------------------------------------
// Kernel 1: per-node gated dense + segment-sum into pooled [G, 64]
//
// Combined GEMM per block of BM=128 contiguous nodes:
//   A[n][k] = k<64 ? h[n][k] : x[n][k-64]          (BM x 128)
//   i_pre[n][d] = sum_{k<128} A[n][k]*Wi[k][d]     (K=128)
//   j_pre[n][d] = sum_{k<64}  A[n][k]*Wj[k][d]     (K=64, h only)
//   RR = sigmoid(tanh(i_pre+bi)) * relu(j_pre+bj)
//   pooled[seg[n]][d] += RR[n][d]                   (seg ids sorted)
//
// Thread map (256 threads): dg = t&15 -> dims {4dg..4dg+3} (i) and +64 (j);
// ng = t>>4 -> nodes {ng+16*i2}. Each thread: 8 nodes x 4 dim-pairs.
// ---------------------------------------------------------------------------
#define BM 128
#define ASTRIDE 36          // 32 k + 4 pad floats (keeps float4 align, kills k-conflicts)
#define MAXSEG 16

__global__ __launch_bounds__(256) void node_gemm_pool(
    const float* __restrict__ x, const float* __restrict__ h,
    const float* __restrict__ Wi, const float* __restrict__ bi,
    const float* __restrict__ Wj, const float* __restrict__ bj,
    const int* __restrict__ seg, float* __restrict__ pooled, int Nn)
{
  __shared__ float Alds[BM * ASTRIDE];      // [node][k]  18.4 KB
  __shared__ float Blds[32 * 128];          // [k][d]     16 KB
  __shared__ float seg_acc[MAXSEG * 64];    //            4 KB
  __shared__ int   seg_lds[BM];

  const int t = threadIdx.x;
  const int node_base = blockIdx.x * BM;

  for (int i2 = t; i2 < MAXSEG * 64; i2 += 256) seg_acc[i2] = 0.f;
  if (t < BM) {
    int nidx = node_base + t;
    if (nidx >= Nn) nidx = Nn - 1;
    seg_lds[t] = seg[nidx];
  }

  const int dg = t & 15, ng = t >> 4;
  const int d0 = dg * 4;

  float acc_i[8][4], acc_j[8][4];
#pragma unroll
  for (int i2 = 0; i2 < 8; ++i2)
#pragma unroll
    for (int d2 = 0; d2 < 4; ++d2) { acc_i[i2][d2] = 0.f; acc_j[i2][d2] = 0.f; }

  for (int kt = 0; kt < 4; ++kt) {
    __syncthreads();
    // ---- stage A tile: 128 nodes x 32 k ----
    {
      const int k0 = kt * 32;
      const float* __restrict__ src = (k0 < 64) ? h : x;
      const int kof = k0 & 63;
#pragma unroll
      for (int p = 0; p < 4; ++p) {
        int fi = t + p * 256;            // float4 index, 0..1023
        int n  = fi >> 3;                // 0..127
        int k4 = (fi & 7) * 4;           // 0..28
        int nidx = node_base + n;
        if (nidx >= Nn) nidx = Nn - 1;   // N=2e6 is divisible by 128; safety only
        const float4 v = *(const float4*)&src[(size_t)nidx * 64 + kof + k4];
        *(float4*)&Alds[n * ASTRIDE + k4] = v;
      }
    }
    // ---- stage B tile: 32 k x 128 d  ([Wi | Wj-or-0]) ----
    {
      const int k0 = kt * 32;
#pragma unroll
      for (int p = 0; p < 4; ++p) {
        int fi = t + p * 256;
        int kl = fi >> 5;                // 0..31
        int dd = (fi & 31) * 4;          // 0..124
        int kg = k0 + kl;
        float4 v;
        if (dd < 64)       v = *(const float4*)&Wi[kg * 64 + dd];
        else if (kg < 64)  v = *(const float4*)&Wj[kg * 64 + (dd - 64)];
        else               v = make_float4(0.f, 0.f, 0.f, 0.f);
        *(float4*)&Blds[kl * 128 + dd] = v;
      }
    }
    __syncthreads();
    // ---- compute ----
    if (kt < 2) {   // k < 64: both i and j accumulate
#pragma unroll 4
      for (int kk = 0; kk < 32; ++kk) {
        float a[8];
#pragma unroll
        for (int i2 = 0; i2 < 8; ++i2) a[i2] = Alds[(ng + 16 * i2) * ASTRIDE + kk];
        float bI[4], bJ[4];
        *(float4*)bI = *(const float4*)&Blds[kk * 128 + d0];
        *(float4*)bJ = *(const float4*)&Blds[kk * 128 + 64 + d0];
#pragma unroll
        for (int i2 = 0; i2 < 8; ++i2)
#pragma unroll
          for (int d2 = 0; d2 < 4; ++d2) {
            acc_i[i2][d2] = fmaf(a[i2], bI[d2], acc_i[i2][d2]);
            acc_j[i2][d2] = fmaf(a[i2], bJ[d2], acc_j[i2][d2]);
          }
      }
    } else {        // k >= 64: only i accumulates (x part)
#pragma unroll 4
      for (int kk = 0; kk < 32; ++kk) {
        float a[8];
#pragma unroll
        for (int i2 = 0; i2 < 8; ++i2) a[i2] = Alds[(ng + 16 * i2) * ASTRIDE + kk];
        float bI[4];
        *(float4*)bI = *(const float4*)&Blds[kk * 128 + d0];
#pragma unroll
        for (int i2 = 0; i2 < 8; ++i2)
#pragma unroll
          for (int d2 = 0; d2 < 4; ++d2)
            acc_i[i2][d2] = fmaf(a[i2], bI[d2], acc_i[i2][d2]);
      }
    }
  }

  // ---- epilogue: activations + gated product ----
  float biv[4], bjv[4];
  *(float4*)biv = *(const float4*)&bi[d0];
  *(float4*)bjv = *(const float4*)&bj[d0];
  float rr[8][4];
#pragma unroll
  for (int i2 = 0; i2 < 8; ++i2) {
    bool valid = (node_base + ng + 16 * i2) < Nn;
#pragma unroll
    for (int d2 = 0; d2 < 4; ++d2) {
      float ip = acc_i[i2][d2] + biv[d2];
      float jp = acc_j[i2][d2] + bjv[d2];
      float th = 1.f - 2.f / (__expf(2.f * ip) + 1.f);   // tanh
      float sg = 1.f / (1.f + __expf(-th));              // sigmoid
      float v = sg * fmaxf(jp, 0.f);
      rr[i2][d2] = valid ? v : 0.f;
    }
  }

  // ---- segment accumulation (ids sorted -> contiguous runs) ----
  const int seg0 = seg_lds[0];
  const int nseg = seg_lds[BM - 1] - seg0 + 1;   // block-uniform
  if (nseg <= MAXSEG) {
    int cur = seg_lds[ng] - seg0;
    float s0 = rr[0][0], s1 = rr[0][1], s2 = rr[0][2], s3 = rr[0][3];
#pragma unroll
    for (int i2 = 1; i2 < 8; ++i2) {
      int rs = seg_lds[ng + 16 * i2] - seg0;
      if (rs != cur) {
        atomicAdd(&seg_acc[cur * 64 + d0 + 0], s0);
        atomicAdd(&seg_acc[cur * 64 + d0 + 1], s1);
        atomicAdd(&seg_acc[cur * 64 + d0 + 2], s2);
        atomicAdd(&seg_acc[cur * 64 + d0 + 3], s3);
        cur = rs; s0 = rr[i2][0]; s1 = rr[i2][1]; s2 = rr[i2][2]; s3 = rr[i2][3];
      } else {
        s0 += rr[i2][0]; s1 += rr[i2][1]; s2 += rr[i2][2]; s3 += rr[i2][3];
      }
    }
    atomicAdd(&seg_acc[cur * 64 + d0 + 0], s0);
    atomicAdd(&seg_acc[cur * 64 + d0 + 1], s1);
    atomicAdd(&seg_acc[cur * 64 + d0 + 2], s2);
    atomicAdd(&seg_acc[cur * 64 + d0 + 3], s3);
    __syncthreads();
    for (int idx = t; idx < nseg * 64; idx += 256) {
      int rs = idx >> 6, dd = idx & 63;
      unsafeAtomicAdd(&pooled[(size_t)(seg0 + rs) * 64 + dd], seg_acc[idx]);
    }
  } else {
    // improbable fallback (a 128-node window spanning >16 segments)
#pragma unroll
    for (int i2 = 0; i2 < 8; ++i2) {
      int sg_ = seg_lds[ng + 16 * i2];
#pragma unroll
      for (int d2 = 0; d2 < 4; ++d2)
        unsafeAtomicAdd(&pooled[(size_t)sg_ * 64 + d0 + d2], rr[i2][d2]);
    }
  }
}

// ---------------------------------------------------------------------------
// Kernel 2: BN (inference) -> relu(Dense 64->256) -> Dense 256->1
// one block (256 threads) per graph
// ---------------------------------------------------------------------------
__global__ __launch_bounds__(256) void readout(
    const float* __restrict__ pooled,
    const float* __restrict__ gamma, const float* __restrict__ beta,
    const float* __restrict__ mean, const float* __restrict__ var,
    const float* __restrict__ Wh, const float* __restrict__ bh,
    const float* __restrict__ Wo, const float* __restrict__ bo,
    float* __restrict__ out)
{
  __shared__ float bn[64];
  __shared__ float red[4];
  const int g = blockIdx.x;
  const int t = threadIdx.x;
  if (t < 64) {
    float p = pooled[(size_t)g * 64 + t];
    bn[t] = (p - mean[t]) * rsqrtf(var[t] + BN_EPS) * gamma[t] + beta[t];
  }
  __syncthreads();
  float acc = bh[t];
#pragma unroll 16
  for (int k = 0; k < 64; ++k)
    acc = fmaf(bn[k], Wh[k * 256 + t], acc);
  float c = fmaxf(acc, 0.f) * Wo[t];
#pragma unroll
  for (int off = 32; off > 0; off >>= 1)
    c += __shfl_down(c, off, 64);
  if ((t & 63) == 0) red[t >> 6] = c;
  __syncthreads();
  if (t == 0) out[g] = red[0] + red[1] + red[2] + red[3] + bo[0];
}

extern "C" void kernel_launch(void* const* d_in, const int* in_sizes, int n_in,
                              void* d_out, int out_size, void* d_ws, size_t ws_size,
                              hipStream_t stream) {
  const float* x     = (const float*)d_in[0];
  const float* h     = (const float*)d_in[1];
  const float* Wi    = (const float*)d_in[2];
  const float* bi    = (const float*)d_in[3];
  const float* Wj    = (const float*)d_in[4];
  const float* bj    = (const float*)d_in[5];
  const float* gamma = (const float*)d_in[6];
  const float* beta  = (const float*)d_in[7];
  const float* mmean = (const float*)d_in[8];
  const float* mvar  = (const float*)d_in[9];
  const float* Wh    = (const float*)d_in[10];
  const float* bh    = (const float*)d_in[11];
  const float* Wo    = (const float*)d_in[12];
  const float* bo    = (const float*)d_in[13];
  const int*   seg   = (const int*)d_in[14];

  const int Nn = in_sizes[0] / 64;
  const int G  = out_size;

  float* pooled = (float*)d_ws;
  hipMemsetAsync(pooled, 0, (size_t)G * 64 * sizeof(float), stream);

  const int nblk = (Nn + BM - 1) / BM;
  node_gemm_pool<<<nblk, 256, 0, stream>>>(x, h, Wi, bi, Wj, bj, seg, pooled, Nn);
  readout<<<G, 256, 0, stream>>>(pooled, gamma, beta, mmean, mvar, Wh, bh, Wo, bo,
                                 (float*)d_out);
}

// Round 2
// 1069.583 us; speedup vs baseline: 1.4169x; 1.4169x over previous
//
#include <hip/hip_runtime.h>
#include <hip/hip_bf16.h>

#define BN_EPS 1e-3f
#define NB 1024
#define MAXSEG 40

typedef __attribute__((ext_vector_type(8))) short short8;
typedef __attribute__((ext_vector_type(4))) float floatx4;

__device__ __forceinline__ unsigned short bf16rne(float f) {
  union { float f; unsigned int u; } v; v.f = f;
  unsigned int u = v.u;
  u += 0x7fffu + ((u >> 16) & 1u);          // round-to-nearest-even
  return (unsigned short)(u >> 16);
}

// ---------------------------------------------------------------------------
// Kernel 1: bf16-MFMA gated dense + segment pool.
// Block = 256 thr = 4 waves; each wave-tile = 16 nodes x 128 output cols
// (cols 0..63 = i-gate, 64..127 = j-gate). A-frags: global fp32 -> cvt ->
// regs (no LDS). B = [Wi | Wj] staged once per block as bf16 [n][k],
// row stride 136 (272 B) -> conflict-free ds_read_b128 fragments.
// C layout (m89/m91): col = lane&15, row(node) = (lane>>4)*4 + reg.
// A layout: m = lane&15, k = (lane>>4)*8 + j.
// ---------------------------------------------------------------------------
__global__ __launch_bounds__(256) void gated_mfma_pool(
    const float* __restrict__ x, const float* __restrict__ h,
    const float* __restrict__ Wi, const float* __restrict__ bi,
    const float* __restrict__ Wj, const float* __restrict__ bj,
    const int* __restrict__ seg, float* __restrict__ pooled,
    int Nn, int chunk)
{
  __shared__ unsigned short Bl[128 * 136];   // 34.8 KB
  __shared__ float seg_acc[MAXSEG * 64];     // 10.2 KB

  const int t = threadIdx.x;
  const int cstart = blockIdx.x * chunk;
  if (cstart >= Nn) return;
  const int cend = min(cstart + chunk, Nn);

  // ---- stage B: Bl[n][k] = bf16(W[k][n]) ----
  for (int idx = t; idx < 64 * 128; idx += 256) {        // Wi: n<64, K=128
    int n = idx & 63, k = idx >> 6;
    Bl[n * 136 + k] = bf16rne(Wi[k * 64 + n]);
  }
  for (int idx = t; idx < 64 * 64; idx += 256) {         // Wj: n>=64, K=64
    int n = idx & 63, k = idx >> 6;
    Bl[(64 + n) * 136 + k] = bf16rne(Wj[k * 64 + n]);
  }
  for (int idx = t; idx < MAXSEG * 64; idx += 256) seg_acc[idx] = 0.f;

  const int s_lo = seg[cstart];
  const int s_hi = seg[cend - 1];
  const int nseg = s_hi - s_lo + 1;
  const bool fb = (nseg > MAXSEG);           // improbable fallback

  __syncthreads();

  const int w = t >> 6, l = t & 63;
  const int m = l & 15, q = l >> 4;
  const int q8 = q * 8;

  float biv[4], bjv[4];
#pragma unroll
  for (int nc = 0; nc < 4; ++nc) { biv[nc] = bi[nc * 16 + m]; bjv[nc] = bj[nc * 16 + m]; }

  for (int tb0 = cstart; tb0 < cend; tb0 += 64) {
    const int tb = tb0 + w * 16;
    if (tb >= Nn) continue;

    // ---- A fragments: row m = lane&15, k-run = q*8 ----
    int nA = tb + m; if (nA >= Nn) nA = Nn - 1;
    const float* hrow = h + (size_t)nA * 64;
    const float* xrow = x + (size_t)nA * 64;
    short8 afr[4];
#pragma unroll
    for (int kc = 0; kc < 4; ++kc) {
      const float* src = (kc < 2) ? (hrow + kc * 32 + q8) : (xrow + (kc - 2) * 32 + q8);
      float4 v0 = *(const float4*)src;
      float4 v1 = *(const float4*)(src + 4);
      short8 f;
      f[0] = bf16rne(v0.x); f[1] = bf16rne(v0.y); f[2] = bf16rne(v0.z); f[3] = bf16rne(v0.w);
      f[4] = bf16rne(v1.x); f[5] = bf16rne(v1.y); f[6] = bf16rne(v1.z); f[7] = bf16rne(v1.w);
      afr[kc] = f;
    }

    floatx4 acc[8];
#pragma unroll
    for (int nc = 0; nc < 8; ++nc) acc[nc] = (floatx4){0.f, 0.f, 0.f, 0.f};

#pragma unroll
    for (int kc = 0; kc < 4; ++kc) {
      const int nl = (kc < 2) ? 8 : 4;       // j-cols only consume h (k<64)
#pragma unroll
      for (int nc = 0; nc < 8; ++nc) {
        if (nc >= nl) break;
        const short8 bfr = *(const short8*)&Bl[(nc * 16 + m) * 136 + kc * 32 + q8];
        acc[nc] = __builtin_amdgcn_mfma_f32_16x16x32_bf16(afr[kc], bfr, acc[nc], 0, 0, 0);
      }
    }

    // ---- epilogue: this lane owns nodes nb4..nb4+3, cols nc*16+m ----
    const int nb4 = tb + q * 4;
    int s4[4];
    if (nb4 + 4 <= Nn) {
      int4 sv = *(const int4*)&seg[nb4];
      s4[0] = sv.x; s4[1] = sv.y; s4[2] = sv.z; s4[3] = sv.w;
    } else {
#pragma unroll
      for (int r = 0; r < 4; ++r) s4[r] = seg[min(nb4 + r, Nn - 1)];
    }

#pragma unroll
    for (int nc = 0; nc < 4; ++nc) {
      const int d = nc * 16 + m;
      float rr[4];
#pragma unroll
      for (int r = 0; r < 4; ++r) {
        float ip = acc[nc][r] + biv[nc];
        float jp = acc[nc + 4][r] + bjv[nc];
        float th = 1.f - 2.f / (__expf(2.f * ip) + 1.f);   // tanh
        float sg = 1.f / (1.f + __expf(-th));              // sigmoid
        float v = sg * fmaxf(jp, 0.f);
        rr[r] = (nb4 + r < Nn) ? v : 0.f;
      }
      if (!fb) {
        float run = rr[0]; int cs = s4[0] - s_lo;
#pragma unroll
        for (int r = 1; r < 4; ++r) {
          int ns = s4[r] - s_lo;
          if (ns == cs) { run += rr[r]; }
          else { atomicAdd(&seg_acc[cs * 64 + d], run); cs = ns; run = rr[r]; }
        }
        atomicAdd(&seg_acc[cs * 64 + d], run);
      } else {
#pragma unroll
        for (int r = 0; r < 4; ++r)
          unsafeAtomicAdd(&pooled[(size_t)s4[r] * 64 + d], rr[r]);
      }
    }
  }

  __syncthreads();
  if (!fb) {
    for (int idx = t; idx < nseg * 64; idx += 256)
      unsafeAtomicAdd(&pooled[(size_t)(s_lo + (idx >> 6)) * 64 + (idx & 63)], seg_acc[idx]);
  }
}

// ---------------------------------------------------------------------------
// Kernel 2: BN -> relu(64->256) -> 256->1, 8 graphs per block.
// Thread t owns hidden unit t; one Wh load feeds 8 graphs' FMAs.
// ---------------------------------------------------------------------------
__global__ __launch_bounds__(256) void readout8(
    const float* __restrict__ pooled, const float* __restrict__ gamma,
    const float* __restrict__ beta, const float* __restrict__ mean,
    const float* __restrict__ var, const float* __restrict__ Wh,
    const float* __restrict__ bh, const float* __restrict__ Wo,
    const float* __restrict__ bo, float* __restrict__ out, int G)
{
  __shared__ float bn[8 * 64];
  __shared__ float red[4][8];
  const int t = threadIdx.x;
  const int g0 = blockIdx.x * 8;

  for (int idx = t; idx < 512; idx += 256) {
    int g = idx >> 6, d = idx & 63;
    int gg = min(g0 + g, G - 1);
    float p = pooled[(size_t)gg * 64 + d];
    bn[idx] = (p - mean[d]) * rsqrtf(var[d] + BN_EPS) * gamma[d] + beta[d];
  }
  __syncthreads();

  float acc[8];
#pragma unroll
  for (int g = 0; g < 8; ++g) acc[g] = 0.f;
#pragma unroll 8
  for (int k = 0; k < 64; ++k) {
    float wv = Wh[k * 256 + t];
#pragma unroll
    for (int g = 0; g < 8; ++g) acc[g] = fmaf(bn[g * 64 + k], wv, acc[g]);
  }

  const float bht = bh[t], wot = Wo[t];
  const int lane = t & 63, wid = t >> 6;
#pragma unroll
  for (int g = 0; g < 8; ++g) {
    float c = fmaxf(acc[g] + bht, 0.f) * wot;
#pragma unroll
    for (int off = 32; off > 0; off >>= 1) c += __shfl_down(c, off, 64);
    if (lane == 0) red[wid][g] = c;
  }
  __syncthreads();
  if (t < 8 && g0 + t < G)
    out[g0 + t] = red[0][t] + red[1][t] + red[2][t] + red[3][t] + bo[0];
}

extern "C" void kernel_launch(void* const* d_in, const int* in_sizes, int n_in,
                              void* d_out, int out_size, void* d_ws, size_t ws_size,
                              hipStream_t stream) {
  const float* x     = (const float*)d_in[0];
  const float* h     = (const float*)d_in[1];
  const float* Wi    = (const float*)d_in[2];
  const float* bi    = (const float*)d_in[3];
  const float* Wj    = (const float*)d_in[4];
  const float* bj    = (const float*)d_in[5];
  const float* gamma = (const float*)d_in[6];
  const float* beta  = (const float*)d_in[7];
  const float* mmean = (const float*)d_in[8];
  const float* mvar  = (const float*)d_in[9];
  const float* Wh    = (const float*)d_in[10];
  const float* bh    = (const float*)d_in[11];
  const float* Wo    = (const float*)d_in[12];
  const float* bo    = (const float*)d_in[13];
  const int*   seg   = (const int*)d_in[14];

  const int Nn = in_sizes[0] / 64;
  const int G  = out_size;

  float* pooled = (float*)d_ws;
  hipMemsetAsync(pooled, 0, (size_t)G * 64 * sizeof(float), stream);

  const int tiles64 = (Nn + 63) / 64;
  const int gpb = (tiles64 + NB - 1) / NB;
  const int chunk = gpb * 64;

  gated_mfma_pool<<<NB, 256, 0, stream>>>(x, h, Wi, bi, Wj, bj, seg, pooled, Nn, chunk);
  readout8<<<(G + 7) / 8, 256, 0, stream>>>(pooled, gamma, beta, mmean, mvar,
                                            Wh, bh, Wo, bo, (float*)d_out, G);
}